// Round 1
// baseline (281.858 us; speedup 1.0000x reference)
//
#include <hip/hip_runtime.h>

#define BB 4
#define NN 2048
#define INF 256
#define HH 8
#define DD 32
#define ALPHA 0.2f

typedef __attribute__((ext_vector_type(8))) short short8;
typedef __attribute__((ext_vector_type(4))) float f32x4;
typedef __attribute__((ext_vector_type(4))) int i32x4;

// LDS pad: 260 floats/row -> 16B-aligned b128 reads, odd-ish bank spread
#define WPAD 260

__device__ __forceinline__ unsigned short f32_to_bf16_rne(float v) {
    unsigned int bits = __float_as_uint(v);
    unsigned int r = (bits + 0x7fffu + ((bits >> 16) & 1u)) >> 16;
    return (unsigned short)r;
}

// Kernel 1: Wh = x @ W  (fp32), epilogue: e_src/e_dst + WhT (bf16, d-major)
// grid: B*H*(N/64) blocks of 256 threads
__global__ __launch_bounds__(256) void wh_kernel(
    const float* __restrict__ x, const float* __restrict__ W,
    const float* __restrict__ a, unsigned short* __restrict__ whT,
    float* __restrict__ esrc, float* __restrict__ edst)
{
    __shared__ float lds[32 * WPAD];
    const int t = threadIdx.x;
    const int blk = blockIdx.x;       // ((b*H + h)*32 + nt)
    const int nt = blk & 31;
    const int bh = blk >> 5;          // b*H + h
    const int h  = bh & 7;
    const int b  = bh >> 3;
    const int d  = t & 31;
    const int g  = t >> 5;            // 0..7

    // stage W^T into LDS: lds[d][f]
    #pragma unroll
    for (int pass = 0; pass < 32; ++pass) {
        int f = pass * 8 + g;
        lds[d * WPAD + f] = W[(h * INF + f) * DD + d];
    }
    __syncthreads();

    const int nbase = nt * 64 + g * 8;
    const float* xrow = x + ((size_t)b * NN + nbase) * INF;

    float acc[8];
    #pragma unroll
    for (int rr = 0; rr < 8; ++rr) acc[rr] = 0.f;

    for (int f0 = 0; f0 < INF; f0 += 4) {
        f32x4 w4 = *(const f32x4*)&lds[d * WPAD + f0];
        #pragma unroll
        for (int rr = 0; rr < 8; ++rr) {
            f32x4 x4 = *(const f32x4*)&xrow[rr * INF + f0];
            acc[rr] += w4[0]*x4[0] + w4[1]*x4[1] + w4[2]*x4[2] + w4[3]*x4[3];
        }
    }
    __syncthreads();   // before aliasing LDS for the transpose buffer

    const float asrc = a[h * 64 + d];
    const float adst = a[h * 64 + 32 + d];

    #pragma unroll
    for (int rr = 0; rr < 8; ++rr) {
        float wv = acc[rr];
        lds[d * 65 + g * 8 + rr] = wv;   // [d][n_local], pad 65
        float u = wv * asrc;
        float v = wv * adst;
        #pragma unroll
        for (int off = 1; off <= 16; off <<= 1) {
            u += __shfl_xor(u, off, 64);
            v += __shfl_xor(v, off, 64);
        }
        if (d == 0) {
            esrc[bh * NN + nbase + rr] = u;
            edst[bh * NN + nbase + rr] = v;
        }
    }
    __syncthreads();

    // coalesced bf16 store of WhT[d][n]
    const int dd2 = t >> 3;           // 0..31
    const int n0  = (t & 7) * 8;
    short8 o8;
    #pragma unroll
    for (int c = 0; c < 8; ++c)
        o8[c] = (short)f32_to_bf16_rne(lds[dd2 * 65 + n0 + c]);
    *(short8*)&whT[((size_t)bh * 32 + dd2) * NN + nt * 64 + n0] = o8;
}

// Kernel 2: flash-style GAT attention. grid: B*(N/16) blocks of 512 threads
// (8 waves = 8 heads). One wave: 16 i-rows x all j for one head.
__global__ __launch_bounds__(512) void attn_kernel(
    const int* __restrict__ adj, const unsigned short* __restrict__ whT,
    const float* __restrict__ esrc, const float* __restrict__ edst,
    float* __restrict__ out)
{
    const int t = threadIdx.x;
    const int h = t >> 6;
    const int l = t & 63;
    const int m = l & 15;     // A-frag row / C col / B col
    const int q = l >> 4;     // quad: k-group
    const int blk = blockIdx.x;
    const int it = blk & 127;
    const int b  = blk >> 7;
    const int bh = b * HH + h;
    const int i0 = it * 16;

    const float ei = esrc[bh * NN + i0 + m];
    const int* adjrow = adj + ((size_t)b * NN + i0 + m) * NN;
    const unsigned short* bt0 = whT + ((size_t)bh * 32 + m) * NN;        // d = m
    const unsigned short* bt1 = whT + ((size_t)bh * 32 + 16 + m) * NN;   // d = 16+m
    const float* ejrow = edst + bh * NN;

    f32x4 acc0 = {0.f, 0.f, 0.f, 0.f};
    f32x4 acc1 = {0.f, 0.f, 0.f, 0.f};
    float den = 0.f;

    for (int j0 = 0; j0 < NN; j0 += 32) {
        const int jb = j0 + q * 8;
        i32x4 a0 = *(const i32x4*)&adjrow[jb];
        i32x4 a1 = *(const i32x4*)&adjrow[jb + 4];
        f32x4 e0 = *(const f32x4*)&ejrow[jb];
        f32x4 e1 = *(const f32x4*)&ejrow[jb + 4];
        short8 b0 = *(const short8*)&bt0[jb];
        short8 b1 = *(const short8*)&bt1[jb];

        short8 afr;
        #pragma unroll
        for (int jj = 0; jj < 8; ++jj) {
            float ej = (jj < 4) ? e0[jj] : e1[jj - 4];
            int   ad = (jj < 4) ? a0[jj] : a1[jj - 4];
            float z  = ei + ej;
            float s  = fmaxf(z, ALPHA * z);      // leakyReLU
            float pv = __expf(s);                // no max-subtract: s <= ~12
            pv = ad ? pv : 0.f;                  // adjacency mask -> exact 0
            den += pv;
            afr[jj] = (short)f32_to_bf16_rne(pv);
        }
        acc0 = __builtin_amdgcn_mfma_f32_16x16x32_bf16(afr, b0, acc0, 0, 0, 0);
        acc1 = __builtin_amdgcn_mfma_f32_16x16x32_bf16(afr, b1, acc1, 0, 0, 0);
    }

    // reduce denominator across the 4 quads: lane x ends with den of row (x&15)
    den += __shfl_xor(den, 16, 64);
    den += __shfl_xor(den, 32, 64);

    #pragma unroll
    for (int r = 0; r < 4; ++r) {
        int ir = q * 4 + r;                      // C row
        float dv = __shfl(den, ir, 64);
        float inv = 1.0f / dv;
        size_t base = ((size_t)b * NN + i0 + ir) * (HH * DD) + h * DD;
        out[base + m]      = acc0[r] * inv;
        out[base + 16 + m] = acc1[r] * inv;
    }
}

extern "C" void kernel_launch(void* const* d_in, const int* in_sizes, int n_in,
                              void* d_out, int out_size, void* d_ws, size_t ws_size,
                              hipStream_t stream) {
    const float* x   = (const float*)d_in[0];
    const int*   adj = (const int*)d_in[1];
    const float* W   = (const float*)d_in[2];
    const float* a   = (const float*)d_in[3];
    float* out = (float*)d_out;

    // workspace: WhT bf16 [B*H][32][N] (4 MB) + esrc + edst (256 KB each)
    unsigned short* whT = (unsigned short*)d_ws;
    float* esrc = (float*)((char*)d_ws + (size_t)BB * HH * 32 * NN * sizeof(unsigned short));
    float* edst = esrc + BB * HH * NN;

    wh_kernel<<<dim3(BB * HH * (NN / 64)), dim3(256), 0, stream>>>(x, W, a, whT, esrc, edst);
    attn_kernel<<<dim3(BB * (NN / 16)), dim3(512), 0, stream>>>(adj, whT, esrc, edst, out);
}

// Round 2
// 233.725 us; speedup vs baseline: 1.2059x; 1.2059x over previous
//
#include <hip/hip_runtime.h>

#define BB 4
#define NN 2048
#define INF 256
#define HH 8
#define DD 32
#define LOG2E 1.4426950408889634f

typedef __attribute__((ext_vector_type(8))) short short8;
typedef __attribute__((ext_vector_type(4))) float f32x4;
typedef __attribute__((ext_vector_type(4))) int i32x4;

#define XB_STRIDE 264   // bf16 units; 264*2B rows keep b128 frags 2-way-max on banks
#define LT_STRIDE 72

__device__ __forceinline__ unsigned short bf16_rhu(float v) {
    return (unsigned short)((__float_as_uint(v) + 0x8000u) >> 16);
}

// we[h][sel][f] = LOG2E * sum_d W[h,f,d] * a[h, sel*32+d]   (16 blocks x 256)
__global__ __launch_bounds__(256) void we_kernel(
    const float* __restrict__ W, const float* __restrict__ a,
    float* __restrict__ we_g)
{
    const int v = blockIdx.x;        // h*2 + sel
    const int h = v >> 1, sel = v & 1;
    const int f = threadIdx.x;
    const float* wr = W + ((size_t)h * INF + f) * DD;
    const float* av = a + h * 2 * DD + sel * DD;
    float acc = 0.f;
    #pragma unroll
    for (int d = 0; d < DD; d += 4) {
        f32x4 w4 = *(const f32x4*)&wr[d];
        acc += w4[0]*av[d] + w4[1]*av[d+1] + w4[2]*av[d+2] + w4[3]*av[d+3];
    }
    we_g[v * INF + f] = acc * LOG2E;
}

// Wh via bf16 MFMA (numerator path) + fp32-exact e = x . we (softmax path)
// grid: B*H*(N/64) = 1024 blocks of 256
__global__ __launch_bounds__(256) void wh_kernel(
    const float* __restrict__ x, const float* __restrict__ W,
    const float* __restrict__ we_g, unsigned short* __restrict__ whT,
    float* __restrict__ esrc, float* __restrict__ edst)
{
    __shared__ __align__(16) char smem[52736];
    unsigned short* xb   = (unsigned short*)smem;             // [64][264] bf16
    unsigned short* wtb  = (unsigned short*)(smem + 33792);   // [32][264] bf16 (W^T)
    float*          weld = (float*)(smem + 50688);            // [512]
    unsigned short* ldsT = (unsigned short*)smem;             // alias: [32][72] bf16

    const int t  = threadIdx.x;
    const int nt = blockIdx.x & 31;
    const int bh = blockIdx.x >> 5;
    const int h  = bh & 7;
    const int b  = bh >> 3;
    const int nbase = nt * 64;

    weld[t]       = we_g[h * 512 + t];
    weld[t + 256] = we_g[h * 512 + 256 + t];
    __syncthreads();

    // stage W -> wtb transposed bf16
    {
        const int d  = t & 31;
        const int f0 = t >> 5;
        #pragma unroll
        for (int k = 0; k < 32; ++k) {
            int f = f0 + k * 8;
            wtb[d * XB_STRIDE + f] = bf16_rhu(W[((size_t)(h * INF + f)) * DD + d]);
        }
    }

    // stage x -> xb bf16 (thread owns 256B contiguous) + fp32 e-dots
    {
        const int row = t >> 2;
        const int cq  = (t & 3) * 64;
        const float* xr = x + ((size_t)(b * NN + nbase + row)) * INF + cq;
        float es = 0.f, ed = 0.f;
        #pragma unroll
        for (int p = 0; p < 16; ++p) {
            f32x4 g  = *(const f32x4*)&xr[p * 4];
            f32x4 ws = *(const f32x4*)&weld[cq + p * 4];
            f32x4 wd = *(const f32x4*)&weld[256 + cq + p * 4];
            es += g[0]*ws[0] + g[1]*ws[1] + g[2]*ws[2] + g[3]*ws[3];
            ed += g[0]*wd[0] + g[1]*wd[1] + g[2]*wd[2] + g[3]*wd[3];
            unsigned a0 = __float_as_uint(g[0]) + 0x8000u;
            unsigned a1 = __float_as_uint(g[1]) + 0x8000u;
            unsigned a2 = __float_as_uint(g[2]) + 0x8000u;
            unsigned a3 = __float_as_uint(g[3]) + 0x8000u;
            uint2 pk;
            pk.x = __builtin_amdgcn_perm(a1, a0, 0x07060302u);
            pk.y = __builtin_amdgcn_perm(a3, a2, 0x07060302u);
            *(uint2*)&xb[row * XB_STRIDE + cq + p * 4] = pk;
        }
        es += __shfl_xor(es, 1, 64); es += __shfl_xor(es, 2, 64);
        ed += __shfl_xor(ed, 1, 64); ed += __shfl_xor(ed, 2, 64);
        if ((t & 3) == 0) {
            esrc[bh * NN + nbase + row] = es;
            edst[bh * NN + nbase + row] = ed;
        }
    }
    __syncthreads();

    // K-loop: wave w -> M-tile w (16 rows), both d-tiles
    const int w = t >> 6;
    const int l = t & 63;
    const int m = l & 15;
    const int q = l >> 4;

    f32x4 acc0 = {0.f,0.f,0.f,0.f}, acc1 = {0.f,0.f,0.f,0.f};
    const unsigned short* arow = xb  + (16 * w + m) * XB_STRIDE + q * 8;
    const unsigned short* b0r  = wtb + m * XB_STRIDE + q * 8;
    const unsigned short* b1r  = wtb + (16 + m) * XB_STRIDE + q * 8;
    #pragma unroll
    for (int k0 = 0; k0 < INF; k0 += 32) {
        short8 af  = *(const short8*)&arow[k0];
        short8 bf0 = *(const short8*)&b0r[k0];
        short8 bf1 = *(const short8*)&b1r[k0];
        acc0 = __builtin_amdgcn_mfma_f32_16x16x32_bf16(af, bf0, acc0, 0, 0, 0);
        acc1 = __builtin_amdgcn_mfma_f32_16x16x32_bf16(af, bf1, acc1, 0, 0, 0);
    }
    __syncthreads();   // all waves done reading xb/wtb

    #pragma unroll
    for (int r = 0; r < 4; ++r) {
        int n = 16 * w + q * 4 + r;      // C: row=q*4+r, col=m
        ldsT[m * LT_STRIDE + n]        = bf16_rhu(acc0[r]);
        ldsT[(16 + m) * LT_STRIDE + n] = bf16_rhu(acc1[r]);
    }
    __syncthreads();

    {
        const int d  = t >> 3;
        const int n0 = (t & 7) * 8;
        i32x4 vv = *(const i32x4*)&ldsT[d * LT_STRIDE + n0];
        *(i32x4*)&whT[((size_t)(bh * DD + d)) * NN + nbase + n0] = vv;
    }
}

// flash-style GAT attention, j-split x2. grid: B*(N/16)=512 blocks of 1024
// wave v: head = v&7, js = v>>3 handles j in [js*1024, js*1024+1024)
__global__ __launch_bounds__(1024, 8) void attn_kernel(
    const int* __restrict__ adj, const unsigned short* __restrict__ whT,
    const float* __restrict__ esrc, const float* __restrict__ edst,
    float* __restrict__ out)
{
    __shared__ __align__(16) float cmb[8 * 64 * 12];
    const int t  = threadIdx.x;
    const int v  = t >> 6;
    const int h  = v & 7;
    const int js = v >> 3;
    const int l  = t & 63;
    const int m  = l & 15;
    const int q  = l >> 4;
    const int it = blockIdx.x & 127;
    const int b  = blockIdx.x >> 7;
    const int bh = b * HH + h;
    const int i0 = it * 16;

    const float ei = esrc[bh * NN + i0 + m];            // already * LOG2E
    const int jst = js * (NN / 2);
    const int* adjrow = adj + ((size_t)(b * NN + i0 + m)) * NN + jst;
    const unsigned short* bt0 = whT + ((size_t)(bh * DD + m)) * NN + jst;
    const unsigned short* bt1 = whT + ((size_t)(bh * DD + 16 + m)) * NN + jst;
    const float* ejrow = edst + bh * NN + jst;

    const short8 ones = {0x3F80,0x3F80,0x3F80,0x3F80,0x3F80,0x3F80,0x3F80,0x3F80};
    f32x4 acc0 = {0.f,0.f,0.f,0.f}, acc1 = {0.f,0.f,0.f,0.f}, accD = {0.f,0.f,0.f,0.f};

    for (int j0 = 0; j0 < NN / 2; j0 += 32) {
        const int jb = j0 + q * 8;
        i32x4 ad0 = *(const i32x4*)&adjrow[jb];
        i32x4 ad1 = *(const i32x4*)&adjrow[jb + 4];
        f32x4 e0  = *(const f32x4*)&ejrow[jb];
        f32x4 e1  = *(const f32x4*)&ejrow[jb + 4];
        short8 bf0 = *(const short8*)&bt0[jb];
        short8 bf1 = *(const short8*)&bt1[jb];

        union { unsigned u[4]; short8 s; } cvt;
        #pragma unroll
        for (int pp = 0; pp < 4; ++pp) {
            float ea = (pp < 2) ? e0[2*pp]     : e1[2*pp - 4];
            float eb = (pp < 2) ? e0[2*pp + 1] : e1[2*pp - 3];
            int   Aa = (pp < 2) ? ad0[2*pp]    : ad1[2*pp - 4];
            int   Ab = (pp < 2) ? ad0[2*pp + 1]: ad1[2*pp - 3];
            float ya = ei + ea, yb = ei + eb;
            float sa = fmaxf(ya, 0.2f * ya);            // lrelu commutes with *LOG2E
            float sb = fmaxf(yb, 0.2f * yb);
            sa = Aa ? sa : -150.f;                      // 2^-150 == 0.0f exactly
            sb = Ab ? sb : -150.f;
            float pa = __builtin_amdgcn_exp2f(sa);
            float pb = __builtin_amdgcn_exp2f(sb);
            cvt.u[pp] = __builtin_amdgcn_perm(__float_as_uint(pb) + 0x8000u,
                                              __float_as_uint(pa) + 0x8000u,
                                              0x07060302u);
        }
        acc0 = __builtin_amdgcn_mfma_f32_16x16x32_bf16(cvt.s, bf0, acc0, 0, 0, 0);
        acc1 = __builtin_amdgcn_mfma_f32_16x16x32_bf16(cvt.s, bf1, acc1, 0, 0, 0);
        accD = __builtin_amdgcn_mfma_f32_16x16x32_bf16(cvt.s, ones, accD, 0, 0, 0);
    }

    float* myc = &cmb[(h * 64 + l) * 12];
    if (js == 1) {
        *(f32x4*)&myc[0] = acc0;
        *(f32x4*)&myc[4] = acc1;
        *(f32x4*)&myc[8] = accD;
    }
    __syncthreads();
    if (js == 0) {
        f32x4 o0 = *(const f32x4*)&myc[0];
        f32x4 o1 = *(const f32x4*)&myc[4];
        f32x4 oD = *(const f32x4*)&myc[8];
        #pragma unroll
        for (int r = 0; r < 4; ++r) {
            float den = accD[r] + oD[r];                // accD[r] valid on every lane
            float inv = 1.0f / den;
            int row = q * 4 + r;
            size_t base = ((size_t)(b * NN + i0 + row)) * (HH * DD) + h * DD;
            out[base + m]      = (acc0[r] + o0[r]) * inv;
            out[base + 16 + m] = (acc1[r] + o1[r]) * inv;
        }
    }
}

extern "C" void kernel_launch(void* const* d_in, const int* in_sizes, int n_in,
                              void* d_out, int out_size, void* d_ws, size_t ws_size,
                              hipStream_t stream) {
    const float* x   = (const float*)d_in[0];
    const int*   adj = (const int*)d_in[1];
    const float* W   = (const float*)d_in[2];
    const float* a   = (const float*)d_in[3];
    float* out = (float*)d_out;

    unsigned short* whT = (unsigned short*)d_ws;                       // 4 MB
    float* esrc = (float*)((char*)d_ws + (size_t)BB * HH * DD * NN * 2);
    float* edst = esrc + BB * HH * NN;
    float* we_g = edst + BB * HH * NN;                                 // 16 KB

    we_kernel<<<dim3(16), dim3(256), 0, stream>>>(W, a, we_g);
    wh_kernel<<<dim3(BB * HH * (NN / 64)), dim3(256), 0, stream>>>(x, W, we_g, whT, esrc, edst);
    attn_kernel<<<dim3(BB * (NN / 16)), dim3(1024), 0, stream>>>(adj, whT, esrc, edst, out);
}

// Round 4
// 161.515 us; speedup vs baseline: 1.7451x; 1.4471x over previous
//
#include <hip/hip_runtime.h>

#define BB 4
#define NN 2048
#define INF 256
#define HH 8
#define DD 32
#define LOG2E 1.4426950408889634f

typedef __attribute__((ext_vector_type(8))) short short8;
typedef __attribute__((ext_vector_type(4))) float f32x4;

__device__ __forceinline__ unsigned short bf16_rhu(float v) {
    return (unsigned short)((__float_as_uint(v) + 0x8000u) >> 16);
}

// we_g[k][f] = LOG2E * sum_d W[h,f,d]*a[h, sel*32+d], k = sel*8 + h
__global__ __launch_bounds__(256) void we_kernel(
    const float* __restrict__ W, const float* __restrict__ a, float* __restrict__ we_g)
{
    const int k = blockIdx.x;            // 0..15
    const int h = k & 7, sel = k >> 3;
    const int f = threadIdx.x;
    const float* wr = W + ((size_t)h * INF + f) * DD;
    const float* av = a + h * 2 * DD + sel * DD;
    float acc = 0.f;
    #pragma unroll
    for (int d = 0; d < DD; ++d) acc += wr[d] * av[d];
    we_g[k * INF + f] = acc * LOG2E;
}

// prep: x -> bf16 (coalesced), W -> wT bf16 [h*32+d][f], exact fp32 e-dots
// grid 512 x 256
__global__ __launch_bounds__(256) void prep_kernel(
    const float* __restrict__ x, const float* __restrict__ W,
    const float* __restrict__ we_g, unsigned short* __restrict__ xbf,
    unsigned short* __restrict__ wT, float* __restrict__ esrc, float* __restrict__ edst)
{
    __shared__ __align__(16) float weld[16 * 256];
    const int t = threadIdx.x;
    #pragma unroll
    for (int i = 0; i < 4; ++i)
        *(f32x4*)&weld[i * 1024 + t * 4] = *(const f32x4*)&we_g[i * 1024 + t * 4];
    if (blockIdx.x < 32) {   // W transpose: wT[h*32+d][f]
        #pragma unroll
        for (int r2 = 0; r2 < 8; ++r2) {
            int row = blockIdx.x * 8 + r2;
            int h = row >> 5, d = row & 31;
            wT[row * INF + t] = bf16_rhu(W[((size_t)h * INF + t) * DD + d]);
        }
    }
    __syncthreads();
    const int wv = t >> 6, l = t & 63;
    const int rr = l >> 4, c = l & 15;
    const int gr = blockIdx.x * 16 + wv * 4 + rr;   // 0..8191
    const int b = gr >> 11, n = gr & 2047;
    const float* xr = x + (size_t)gr * INF + c * 16;
    f32x4 xx[4];
    #pragma unroll
    for (int i = 0; i < 4; ++i) xx[i] = *(const f32x4*)&xr[i * 4];
    unsigned pk[8];
    #pragma unroll
    for (int i = 0; i < 8; ++i) {
        unsigned lo = __float_as_uint(xx[i >> 1][(i & 1) * 2]) + 0x8000u;
        unsigned hi = __float_as_uint(xx[i >> 1][(i & 1) * 2 + 1]) + 0x8000u;
        pk[i] = __builtin_amdgcn_perm(hi, lo, 0x07060302u);
    }
    *(uint4*)&xbf[(size_t)gr * INF + c * 16] = *(uint4*)&pk[0];
    *(uint4*)&xbf[(size_t)gr * INF + c * 16 + 8] = *(uint4*)&pk[4];
    #pragma unroll
    for (int k = 0; k < 16; ++k) {
        const float* wk = &weld[k * 256 + c * 16];
        float s = 0.f;
        #pragma unroll
        for (int i = 0; i < 4; ++i) {
            f32x4 w4 = *(const f32x4*)&wk[i * 4];
            s += xx[i][0]*w4[0] + xx[i][1]*w4[1] + xx[i][2]*w4[2] + xx[i][3]*w4[3];
        }
        s += __shfl_xor(s, 1, 64);
        s += __shfl_xor(s, 2, 64);
        s += __shfl_xor(s, 4, 64);
        s += __shfl_xor(s, 8, 64);
        if (c == k) {
            if (k < 8) esrc[(b * 8 + k) * NN + n] = s;
            else       edst[(b * 8 + (k - 8)) * NN + n] = s;
        }
    }
}

// wh GEMM: 128 rows x 64 cols (head-pair) x K=256, output whT2[bh][j/8][d][8] bf16
// grid 256 x 512
__global__ __launch_bounds__(512) void wh_kernel(
    const unsigned short* __restrict__ xbf, const unsigned short* __restrict__ wT,
    unsigned short* __restrict__ whT2)
{
    __shared__ __align__(16) unsigned short xb[128 * 264];
    __shared__ __align__(16) unsigned short wb[64 * 264];
    const int t = threadIdx.x;
    const int hp = blockIdx.x & 3, ntile = (blockIdx.x >> 2) & 15, b = blockIdx.x >> 6;
    const int n0 = ntile * 128;
    #pragma unroll
    for (int p = 0; p < 8; ++p) {
        int flat = p * 4096 + t * 8;
        int row = flat >> 8, col = flat & 255;
        *(short8*)&xb[row * 264 + col] =
            *(const short8*)&xbf[((size_t)b * NN + n0 + row) * INF + col];
    }
    #pragma unroll
    for (int p = 0; p < 4; ++p) {
        int flat = p * 4096 + t * 8;
        int cc = flat >> 8, f = flat & 255;
        *(short8*)&wb[cc * 264 + f] = *(const short8*)&wT[(hp * 64 + cc) * INF + f];
    }
    __syncthreads();
    const int w = t >> 6, l = t & 63;
    const int wm = w & 3, wn = w >> 2;
    const int ml = l & 15, q = l >> 4;
    f32x4 acc[2][2] = {};
    const unsigned short* a0p = &xb[(wm * 32 + ml) * 264 + q * 8];
    const unsigned short* a1p = &xb[(wm * 32 + 16 + ml) * 264 + q * 8];
    const unsigned short* b0p = &wb[(wn * 32 + ml) * 264 + q * 8];
    const unsigned short* b1p = &wb[(wn * 32 + 16 + ml) * 264 + q * 8];
    #pragma unroll
    for (int k0 = 0; k0 < INF; k0 += 32) {
        short8 A0 = *(const short8*)&a0p[k0];
        short8 A1 = *(const short8*)&a1p[k0];
        short8 B0 = *(const short8*)&b0p[k0];
        short8 B1 = *(const short8*)&b1p[k0];
        acc[0][0] = __builtin_amdgcn_mfma_f32_16x16x32_bf16(A0, B0, acc[0][0], 0, 0, 0);
        acc[0][1] = __builtin_amdgcn_mfma_f32_16x16x32_bf16(A0, B1, acc[0][1], 0, 0, 0);
        acc[1][0] = __builtin_amdgcn_mfma_f32_16x16x32_bf16(A1, B0, acc[1][0], 0, 0, 0);
        acc[1][1] = __builtin_amdgcn_mfma_f32_16x16x32_bf16(A1, B1, acc[1][1], 0, 0, 0);
    }
    __syncthreads();
    unsigned short* ldsC = xb;   // [64 col][136]
    #pragma unroll
    for (int mt = 0; mt < 2; ++mt)
        #pragma unroll
        for (int nt = 0; nt < 2; ++nt)
            #pragma unroll
            for (int r = 0; r < 4; ++r) {
                int ct = wn * 32 + nt * 16 + ml;
                int rt = wm * 32 + mt * 16 + q * 4 + r;
                ldsC[ct * 136 + rt] = bf16_rhu(acc[mt][nt][r]);
            }
    __syncthreads();
    #pragma unroll
    for (int p = 0; p < 2; ++p) {
        int g = p * 512 + t;
        int d = g & 31, jo = (g >> 5) & 15, h2 = g >> 9;
        short8 vv = *(const short8*)&ldsC[(h2 * 32 + d) * 136 + jo * 8];
        int bh = b * 8 + hp * 2 + h2;
        *(short8*)&whT2[(((size_t)bh * 256 + ntile * 16 + jo) * 32 + d) * 8] = vv;
    }
}

// attn: 256 blocks (b, 32-row i-tile) x 1024 thr; 16 waves = 8 heads x 2 j-halves.
// adj staged as ballot-bitmask in LDS; whT2 B-loads contiguous; R=2 i-tiles/wave.
// Each js-half covers 1024 j's = 8 chunks of 128.
__global__ __launch_bounds__(1024, 4) void attn_kernel(
    const int* __restrict__ adj, const unsigned short* __restrict__ whT2,
    const float* __restrict__ esrc, const float* __restrict__ edst,
    float* __restrict__ out)
{
    __shared__ __align__(16) unsigned bits[2][2][32][4];   // [dbuf][half][row][128 j bits]
    __shared__ __align__(16) float cmb[8][64][24];
    const int t = threadIdx.x, v = t >> 6, l = t & 63;
    const int h = v & 7, js = v >> 3;
    const int ml = l & 15, q = l >> 4;
    const int it = blockIdx.x & 63, b = blockIdx.x >> 6;
    const int i0 = it * 32;
    const int bh = b * HH + h;
    const float ei0 = esrc[bh * NN + i0 + ml];
    const float ei1 = esrc[bh * NN + i0 + 16 + ml];
    const float* ejp = edst + bh * NN + js * 1024;
    const unsigned short* whb = whT2 + ((size_t)bh * 256 + js * 128) * 256;

    auto stage = [&](int c2, int buf) {
        #pragma unroll
        for (int u = 0; u < 4; ++u) {
            int uid = v * 4 + u;
            int row = uid & 31, half = uid >> 5;
            const int* g = adj + ((size_t)(b * NN + i0 + row)) * NN + half * 1024 + c2 * 128 + l;
            int a0 = g[0], a1 = g[64];
            unsigned long long m0 = __ballot(a0 != 0);
            unsigned long long m1 = __ballot(a1 != 0);
            if (l == 0) {
                uint4 pv = make_uint4((unsigned)m0, (unsigned)(m0 >> 32),
                                      (unsigned)m1, (unsigned)(m1 >> 32));
                *(uint4*)&bits[buf][half][row][0] = pv;
            }
        }
    };

    const short8 ones = {0x3F80, 0x3F80, 0x3F80, 0x3F80, 0x3F80, 0x3F80, 0x3F80, 0x3F80};
    f32x4 acc00 = {}, acc01 = {}, acc10 = {}, acc11 = {}, accD0 = {}, accD1 = {};

    stage(0, 0);
    for (int c = 0; c < 8; ++c) {
        __syncthreads();
        if (c < 7) stage(c + 1, (c + 1) & 1);
        const int buf = c & 1;
        unsigned w0a[4], w1a[4];
        *(uint4*)w0a = *(const uint4*)&bits[buf][js][ml][0];
        *(uint4*)w1a = *(const uint4*)&bits[buf][js][16 + ml][0];
        const float* ejc = ejp + c * 128;
        #pragma unroll
        for (int k = 0; k < 4; ++k) {
            const int jb = k * 32 + q * 8;
            f32x4 ejA = *(const f32x4*)&ejc[jb];
            f32x4 ejB = *(const f32x4*)&ejc[jb + 4];
            const unsigned short* wp = whb + (size_t)(c * 16 + k * 4 + q) * 256;
            short8 B0 = *(const short8*)&wp[ml * 8];
            short8 B1 = *(const short8*)&wp[(16 + ml) * 8];
            unsigned st0 = w0a[k] >> (q * 8);
            unsigned st1 = w1a[k] >> (q * 8);
            union { unsigned u[4]; short8 s; } f0, f1;
            #pragma unroll
            for (int pp = 0; pp < 4; ++pp) {
                float eA = (pp < 2) ? ejA[pp * 2] : ejB[pp * 2 - 4];
                float eB = (pp < 2) ? ejA[pp * 2 + 1] : ejB[pp * 2 - 3];
                unsigned mA0 = (unsigned)__builtin_amdgcn_sbfe(st0, 2 * pp, 1);
                unsigned mB0 = (unsigned)__builtin_amdgcn_sbfe(st0, 2 * pp + 1, 1);
                unsigned mA1 = (unsigned)__builtin_amdgcn_sbfe(st1, 2 * pp, 1);
                unsigned mB1 = (unsigned)__builtin_amdgcn_sbfe(st1, 2 * pp + 1, 1);
                float z; unsigned pa, pb;
                z = ei0 + eA; z = fmaxf(z, 0.2f * z);
                pa = (__float_as_uint(__builtin_amdgcn_exp2f(z)) + 0x8000u) & mA0;
                z = ei0 + eB; z = fmaxf(z, 0.2f * z);
                pb = (__float_as_uint(__builtin_amdgcn_exp2f(z)) + 0x8000u) & mB0;
                f0.u[pp] = __builtin_amdgcn_perm(pb, pa, 0x07060302u);
                z = ei1 + eA; z = fmaxf(z, 0.2f * z);
                pa = (__float_as_uint(__builtin_amdgcn_exp2f(z)) + 0x8000u) & mA1;
                z = ei1 + eB; z = fmaxf(z, 0.2f * z);
                pb = (__float_as_uint(__builtin_amdgcn_exp2f(z)) + 0x8000u) & mB1;
                f1.u[pp] = __builtin_amdgcn_perm(pb, pa, 0x07060302u);
            }
            acc00 = __builtin_amdgcn_mfma_f32_16x16x32_bf16(f0.s, B0, acc00, 0, 0, 0);
            acc01 = __builtin_amdgcn_mfma_f32_16x16x32_bf16(f0.s, B1, acc01, 0, 0, 0);
            accD0 = __builtin_amdgcn_mfma_f32_16x16x32_bf16(f0.s, ones, accD0, 0, 0, 0);
            acc10 = __builtin_amdgcn_mfma_f32_16x16x32_bf16(f1.s, B0, acc10, 0, 0, 0);
            acc11 = __builtin_amdgcn_mfma_f32_16x16x32_bf16(f1.s, B1, acc11, 0, 0, 0);
            accD1 = __builtin_amdgcn_mfma_f32_16x16x32_bf16(f1.s, ones, accD1, 0, 0, 0);
        }
    }

    float* myc = &cmb[h][l][0];
    if (js == 1) {
        *(f32x4*)&myc[0]  = acc00; *(f32x4*)&myc[4]  = acc01;
        *(f32x4*)&myc[8]  = acc10; *(f32x4*)&myc[12] = acc11;
        *(f32x4*)&myc[16] = accD0; *(f32x4*)&myc[20] = accD1;
    }
    __syncthreads();
    if (js == 0) {
        f32x4 o00 = *(const f32x4*)&myc[0],  o01 = *(const f32x4*)&myc[4];
        f32x4 o10 = *(const f32x4*)&myc[8],  o11 = *(const f32x4*)&myc[12];
        f32x4 oD0 = *(const f32x4*)&myc[16], oD1 = *(const f32x4*)&myc[20];
        #pragma unroll
        for (int r = 0; r < 4; ++r) {
            int ir0 = i0 + q * 4 + r;
            int ir1 = i0 + 16 + q * 4 + r;
            float inv0 = 1.0f / (accD0[r] + oD0[r]);
            float inv1 = 1.0f / (accD1[r] + oD1[r]);
            size_t ba0 = ((size_t)(b * NN + ir0)) * (HH * DD) + h * DD;
            size_t ba1 = ((size_t)(b * NN + ir1)) * (HH * DD) + h * DD;
            out[ba0 + ml]      = (acc00[r] + o00[r]) * inv0;
            out[ba0 + 16 + ml] = (acc01[r] + o01[r]) * inv0;
            out[ba1 + ml]      = (acc10[r] + o10[r]) * inv1;
            out[ba1 + 16 + ml] = (acc11[r] + o11[r]) * inv1;
        }
    }
}

extern "C" void kernel_launch(void* const* d_in, const int* in_sizes, int n_in,
                              void* d_out, int out_size, void* d_ws, size_t ws_size,
                              hipStream_t stream) {
    (void)in_sizes; (void)n_in; (void)out_size; (void)ws_size;
    const float* x   = (const float*)d_in[0];
    const int*   adj = (const int*)d_in[1];
    const float* W   = (const float*)d_in[2];
    const float* a   = (const float*)d_in[3];
    float* out = (float*)d_out;

    char* ws = (char*)d_ws;
    unsigned short* whT2 = (unsigned short*)ws;                         // 4 MB
    unsigned short* xbf  = (unsigned short*)(ws + (4u << 20));          // 4 MB
    unsigned short* wT   = (unsigned short*)(ws + (8u << 20));          // 128 KB
    float* esrc = (float*)(ws + (8u << 20) + (128u << 10));             // 256 KB
    float* edst = esrc + BB * HH * NN;                                  // 256 KB
    float* we_g = edst + BB * HH * NN;                                  // 16 KB

    we_kernel<<<dim3(16), dim3(256), 0, stream>>>(W, a, we_g);
    prep_kernel<<<dim3(512), dim3(256), 0, stream>>>(x, W, we_g, xbf, wT, esrc, edst);
    wh_kernel<<<dim3(256), dim3(512), 0, stream>>>(xbf, wT, whT2);
    attn_kernel<<<dim3(256), dim3(1024), 0, stream>>>(adj, whT2, esrc, edst, out);
}